// Round 1
// baseline (717.170 us; speedup 1.0000x reference)
//
#include <hip/hip_runtime.h>
#include <stdint.h>

// DBSCAN-on-voxel-grid, exact port of the JAX reference for batch_size==1.
// Grid 512x512, eps=1.5 => 8-connected (Moore) adjacency, min_samples=5
// (voxel counts, incl. self), clusters with <20 voxels dropped.
// Single block of 1024 threads; all state in LDS except cluster counts (d_ws).

#define GRIDW 512
#define NWORDS 8192   // 512*512 / 32
#define NGROUPS 4096  // two words (64 cells) per rank group
#define NTHREADS 1024
#define BIGL 0xFFFF

__global__ __launch_bounds__(NTHREADS) void cluster_kernel(
    const float* __restrict__ pts, float* __restrict__ out,
    uint32_t* __restrict__ cnt, int npts) {
  __shared__ uint32_t occ[NWORDS];        // 32 KB occupancy bitmap
  __shared__ uint16_t pre2[NGROUPS];      // 8 KB exclusive popcount prefix per 64 cells
  __shared__ uint16_t labels[8192];       // 16 KB label per compact voxel (BIGL = none/noise)
  __shared__ uint32_t coreflag[256];      // 1 KB bit per compact voxel
  __shared__ uint32_t rootbm[256];        // 1 KB
  __shared__ uint32_t keepbm[256];        // 1 KB
  __shared__ uint16_t rootpre[256];       // 0.5 KB exclusive root-rank prefix per word
  __shared__ uint32_t scanbuf[NTHREADS];  // 4 KB
  __shared__ int sMaxd, sChanged, sM;

  const int tid = threadIdx.x;

  // ---- init ----
  for (int i = tid; i < NWORDS; i += NTHREADS) occ[i] = 0u;
  for (int i = tid; i < 4096; i += NTHREADS) ((uint32_t*)labels)[i] = 0xFFFFFFFFu;
  if (tid < 256) { coreflag[tid] = 0u; rootbm[tid] = 0u; keepbm[tid] = 0u; }
  if (tid == 0) sMaxd = -1;
  __syncthreads();

  // ---- voxelize points, set occupancy bits (cells kept in registers) ----
  int myCell[8];
  for (int k = 0; k < 8; k++) {
    int i = k * NTHREADS + tid;
    int cell = -1;
    if (i < npts) {
      float x = pts[i * 5 + 1];
      float y = pts[i * 5 + 2];
      // identical f32 ops to jnp: (x - (-51.2f)) / 0.2f, floor, int cast
      int cx = (int)floorf((x - (-51.2f)) / 0.2f);
      int cy = (int)floorf((y - (-51.2f)) / 0.2f);
      cx = min(max(cx, 0), GRIDW - 1);
      cy = min(max(cy, 0), GRIDW - 1);
      cell = cy * GRIDW + cx;
      atomicOr(&occ[cell >> 5], 1u << (cell & 31));
    }
    myCell[k] = cell;
  }
  __syncthreads();

  // ---- popcount prefix -> rank(cell) == index into sorted unique cell ids ----
  {
    uint32_t s[4];
    uint32_t tot = 0;
    for (int j = 0; j < 4; j++) {
      int g = tid * 4 + j;
      s[j] = __popc(occ[2 * g]) + __popc(occ[2 * g + 1]);
      tot += s[j];
    }
    scanbuf[tid] = tot;
    __syncthreads();
    for (int off = 1; off < NTHREADS; off <<= 1) {
      uint32_t v = scanbuf[tid];
      uint32_t a = (tid >= off) ? scanbuf[tid - off] : 0u;
      __syncthreads();
      scanbuf[tid] = v + a;
      __syncthreads();
    }
    uint32_t excl = scanbuf[tid] - tot;
    for (int j = 0; j < 4; j++) {
      pre2[tid * 4 + j] = (uint16_t)excl;
      excl += s[j];
    }
    if (tid == NTHREADS - 1) sM = (int)scanbuf[NTHREADS - 1];
  }
  __syncthreads();
  const int M = sM;

  auto rank = [&](int cell) -> int {
    int wi = cell >> 5;
    int r = pre2[cell >> 6];
    if (wi & 1) r += __popc(occ[wi - 1]);
    r += __popc(occ[wi] & ((1u << (cell & 31)) - 1u));
    return r;
  };

  // ---- core test: >=5 occupied voxels in 3x3 (incl self) ----
  for (int wi = tid; wi < NWORDS; wi += NTHREADS) {
    uint32_t w = occ[wi];
    if (!w) continue;
    int r = pre2[wi >> 1] + ((wi & 1) ? __popc(occ[wi - 1]) : 0);
    while (w) {
      int b = __ffs(w) - 1;
      w &= w - 1;
      int cell = (wi << 5) + b;
      int cx = cell & (GRIDW - 1), cy = cell >> 9;
      int c9 = 0;
      for (int dy = -1; dy <= 1; dy++) {
        int ny = cy + dy;
        if ((unsigned)ny >= (unsigned)GRIDW) continue;
        for (int dx = -1; dx <= 1; dx++) {
          int nx = cx + dx;
          if ((unsigned)nx >= (unsigned)GRIDW) continue;
          int nc = ny * GRIDW + nx;
          c9 += (occ[nc >> 5] >> (nc & 31)) & 1;
        }
      }
      if (c9 >= 5) {
        labels[r] = (uint16_t)r;
        atomicOr(&coreflag[r >> 5], 1u << (r & 31));
      }
      r++;
    }
  }
  __syncthreads();

  // ---- connected components over core voxels: async min-label + pointer jump ----
  for (;;) {
    __syncthreads();
    if (tid == 0) sChanged = 0;
    __syncthreads();
    for (int wi = tid; wi < NWORDS; wi += NTHREADS) {
      uint32_t w = occ[wi];
      if (!w) continue;
      int r = pre2[wi >> 1] + ((wi & 1) ? __popc(occ[wi - 1]) : 0);
      while (w) {
        int b = __ffs(w) - 1;
        w &= w - 1;
        int cell = (wi << 5) + b;
        if ((coreflag[r >> 5] >> (r & 31)) & 1) {
          int m = labels[r];
          int cx = cell & (GRIDW - 1), cy = cell >> 9;
          for (int dy = -1; dy <= 1; dy++) {
            int ny = cy + dy;
            if ((unsigned)ny >= (unsigned)GRIDW) continue;
            for (int dx = -1; dx <= 1; dx++) {
              if (dx == 0 && dy == 0) continue;
              int nx = cx + dx;
              if ((unsigned)nx >= (unsigned)GRIDW) continue;
              int nc = ny * GRIDW + nx;
              if ((occ[nc >> 5] >> (nc & 31)) & 1) {
                int nr = rank(nc);
                if ((coreflag[nr >> 5] >> (nr & 31)) & 1) {
                  int lv = labels[nr];
                  if (lv < m) m = lv;
                }
              }
            }
          }
          int m2 = labels[m];  // path compression (m is always a core index)
          if (m2 < m) m = m2;
          if (m < (int)labels[r]) {
            labels[r] = (uint16_t)m;
            sChanged = 1;
          }
        }
        r++;
      }
    }
    __syncthreads();
    if (!sChanged) break;
  }

  // ---- border attach: non-core occupied voxel takes min label of CORE neighbors ----
  for (int wi = tid; wi < NWORDS; wi += NTHREADS) {
    uint32_t w = occ[wi];
    if (!w) continue;
    int r = pre2[wi >> 1] + ((wi & 1) ? __popc(occ[wi - 1]) : 0);
    while (w) {
      int b = __ffs(w) - 1;
      w &= w - 1;
      int cell = (wi << 5) + b;
      if (!((coreflag[r >> 5] >> (r & 31)) & 1)) {
        int m = BIGL;
        int cx = cell & (GRIDW - 1), cy = cell >> 9;
        for (int dy = -1; dy <= 1; dy++) {
          int ny = cy + dy;
          if ((unsigned)ny >= (unsigned)GRIDW) continue;
          for (int dx = -1; dx <= 1; dx++) {
            if (dx == 0 && dy == 0) continue;
            int nx = cx + dx;
            if ((unsigned)nx >= (unsigned)GRIDW) continue;
            int nc = ny * GRIDW + nx;
            if ((occ[nc >> 5] >> (nc & 31)) & 1) {
              int nr = rank(nc);
              if ((coreflag[nr >> 5] >> (nr & 31)) & 1) {
                int lv = labels[nr];
                if (lv < m) m = lv;
              }
            }
          }
        }
        labels[r] = (uint16_t)m;  // BIGL => noise
      }
      r++;
    }
  }
  __syncthreads();

  // ---- roots (core voxel whose label is itself) + dense-rank prefix ----
  for (int r = tid; r < M; r += NTHREADS) {
    if (((coreflag[r >> 5] >> (r & 31)) & 1) && labels[r] == (uint16_t)r)
      atomicOr(&rootbm[r >> 5], 1u << (r & 31));
  }
  __syncthreads();
  {
    uint32_t v = (tid < 256) ? __popc(rootbm[tid]) : 0u;
    scanbuf[tid] = v;
    __syncthreads();
    for (int off = 1; off < 256; off <<= 1) {
      uint32_t x = scanbuf[tid];
      uint32_t a = (tid >= off && tid < 256) ? scanbuf[tid - off] : 0u;
      __syncthreads();
      scanbuf[tid] = x + a;
      __syncthreads();
    }
    if (tid < 256) rootpre[tid] = (uint16_t)(scanbuf[tid] - v);
  }
  __syncthreads();

  // ---- per-cluster voxel counts in global ws (L2-scope atomics) ----
  for (int i = tid; i < 8192; i += NTHREADS) atomicExch(&cnt[i], 0u);
  __threadfence();
  __syncthreads();
  for (int r = tid; r < M; r += NTHREADS) {
    int l = labels[r];
    if (l != BIGL) atomicAdd(&cnt[l], 1u);
  }
  __threadfence();
  __syncthreads();
  for (int r = tid; r < M; r += NTHREADS) {
    if ((rootbm[r >> 5] >> (r & 31)) & 1) {
      uint32_t c = atomicAdd(&cnt[r], 0u);  // L2-coherent read
      if (c >= 20u) atomicOr(&keepbm[r >> 5], 1u << (r & 31));
    }
  }
  __syncthreads();

  // ---- scatter labels back to points; track max kept dense id ----
  for (int k = 0; k < 8; k++) {
    int i = k * NTHREADS + tid;
    if (i >= npts) continue;
    int cell = myCell[k];
    int r = rank(cell);
    int l = labels[r];
    float o = -1.0f;
    if (l != BIGL && ((keepbm[l >> 5] >> (l & 31)) & 1)) {
      int d = rootpre[l >> 5] + __popc(rootbm[l >> 5] & ((1u << (l & 31)) - 1u));
      o = (float)d;
      atomicMax(&sMaxd, d);
    }
    out[i] = o;
  }
  __syncthreads();
  if (tid == 0) out[npts] = (float)(sMaxd + 1);
}

extern "C" void kernel_launch(void* const* d_in, const int* in_sizes, int n_in,
                              void* d_out, int out_size, void* d_ws, size_t ws_size,
                              hipStream_t stream) {
  const float* pts = (const float*)d_in[0];
  int npts = in_sizes[0] / 5;  // points are (N,5) float32
  cluster_kernel<<<1, NTHREADS, 0, stream>>>(pts, (float*)d_out,
                                             (uint32_t*)d_ws, npts);
}

// Round 2
// 199.702 us; speedup vs baseline: 3.5912x; 3.5912x over previous
//
#include <hip/hip_runtime.h>
#include <stdint.h>

// DBSCAN-on-voxel-grid, exact port of the JAX reference for batch_size==1.
// Grid 512x512, eps=1.5 => 8-connected adjacency, min_samples=5 (voxels,
// incl. self), clusters with <20 voxels dropped. Single block, 1024 threads.
// R2: union-find CC (1 merge + 1 compress sweep) replaces iterative min-label
// propagation; SWAR window math makes neighbor ranks VALU-only; counts in LDS.

#define GRIDW 512
#define WPR 16        // bitmap words per row
#define NWORDS 8192   // 512*512/32
#define NTHREADS 1024
#define BIGL 0xFFFF

__device__ __forceinline__ uint16_t cas16(uint16_t* p, uint16_t cmp, uint16_t val) {
  uint32_t* w = (uint32_t*)((uintptr_t)p & ~(uintptr_t)3);
  unsigned sh = ((uintptr_t)p & 2) ? 16u : 0u;
  uint32_t msk = 0xFFFFu << sh;
  uint32_t old = *(volatile uint32_t*)w;
  for (;;) {
    uint16_t cur = (uint16_t)((old >> sh) & 0xFFFFu);
    if (cur != cmp) return cur;
    uint32_t nv = (old & ~msk) | ((uint32_t)val << sh);
    uint32_t prev = atomicCAS(w, old, nv);
    if (prev == old) return cmp;
    old = prev;
  }
}

__device__ __forceinline__ int find16(uint16_t* L, int x) {
  volatile uint16_t* vl = (volatile uint16_t*)L;
  int p = vl[x];
  while (p != x) { x = p; p = vl[x]; }
  return x;
}

// link larger root under smaller => final root == min core rank of component
__device__ __forceinline__ void unite16(uint16_t* L, int a, int b) {
  for (;;) {
    a = find16(L, a);
    b = find16(L, b);
    if (a == b) return;
    int lo = a < b ? a : b;
    int hi = a ^ b ^ lo;
    if (cas16(&L[hi], (uint16_t)hi, (uint16_t)lo) == (uint16_t)hi) return;
    a = lo; b = hi;
  }
}

__global__ __launch_bounds__(NTHREADS) void cluster_kernel(
    const float* __restrict__ pts, float* __restrict__ out, int npts) {
  __shared__ uint32_t occ[NWORDS];        // 32 KB bitmap; reused as cnt[] later
  __shared__ uint16_t pre2[4096];         // 8 KB: excl. popcount prefix / 64 cells
  __shared__ uint16_t labels[8192];       // 16 KB: label per compact voxel rank
  __shared__ uint32_t coreflag[256];      // bit per rank
  __shared__ uint32_t rootbm[256];
  __shared__ uint32_t keepbm[256];
  __shared__ uint16_t rootpre[256];
  __shared__ uint32_t scanbuf[NTHREADS];  // 4 KB
  __shared__ int sMaxd, sM;

  const int tid = threadIdx.x;

  // ---- P0 init ----
  for (int i = tid; i < NWORDS; i += NTHREADS) occ[i] = 0u;
  for (int i = tid; i < 4096; i += NTHREADS) ((uint32_t*)labels)[i] = 0xFFFFFFFFu;
  if (tid < 256) { coreflag[tid] = 0u; rootbm[tid] = 0u; keepbm[tid] = 0u; }
  if (tid == 0) sMaxd = -1;
  __syncthreads();

  // ---- P1 voxelize ----
  int myCell[8];
  for (int k = 0; k < 8; k++) {
    int i = k * NTHREADS + tid;
    int cell = -1;
    if (i < npts) {
      float x = pts[i * 5 + 1];
      float y = pts[i * 5 + 2];
      int cx = (int)floorf((x - (-51.2f)) / 0.2f);  // identical f32 ops to jnp
      int cy = (int)floorf((y - (-51.2f)) / 0.2f);
      cx = min(max(cx, 0), GRIDW - 1);
      cy = min(max(cy, 0), GRIDW - 1);
      cell = cy * GRIDW + cx;
      atomicOr(&occ[cell >> 5], 1u << (cell & 31));
    }
    myCell[k] = cell;
  }
  __syncthreads();

  // ---- P2 popcount prefix: rank(cell) == index into sorted unique cells ----
  {
    uint32_t s[4];
    uint32_t tot = 0;
    for (int j = 0; j < 4; j++) {
      int g = tid * 4 + j;
      s[j] = __popc(occ[2 * g]) + __popc(occ[2 * g + 1]);
      tot += s[j];
    }
    scanbuf[tid] = tot;
    __syncthreads();
    for (int off = 1; off < NTHREADS; off <<= 1) {
      uint32_t v = scanbuf[tid];
      uint32_t a = (tid >= off) ? scanbuf[tid - off] : 0u;
      __syncthreads();
      scanbuf[tid] = v + a;
      __syncthreads();
    }
    uint32_t excl = scanbuf[tid] - tot;
    for (int j = 0; j < 4; j++) {
      pre2[tid * 4 + j] = (uint16_t)excl;
      excl += s[j];
    }
    if (tid == NTHREADS - 1) sM = (int)scanbuf[NTHREADS - 1];
  }
  __syncthreads();
  const int M = sM;

  auto rank = [&](int cell) -> int {
    int wi = cell >> 5;
    int r = pre2[cell >> 6];
    if (wi & 1) r += __popc(occ[wi - 1]);
    r += __popc(occ[wi] & ((1u << (cell & 31)) - 1u));
    return r;
  };

  // ---- P3 per-point ranks (registers; frees occ/pre2 for reuse later) ----
  int myRank[8];
  for (int k = 0; k < 8; k++) myRank[k] = (myCell[k] >= 0) ? rank(myCell[k]) : -1;
  // (no barrier needed: P3 only reads)

  // ---- P4 core test via 3x3 SWAR windows ----
  for (int wi = tid; wi < NWORDS; wi += NTHREADS) {
    uint32_t w = occ[wi];
    if (!w) continue;
    int y = wi >> 4, wx = wi & 15;
    uint32_t lc = wx ? occ[wi - 1] : 0u;
    uint32_t rc = (wx < 15) ? occ[wi + 1] : 0u;
    uint32_t ca = 0, la = 0, ra = 0, cb = 0, lb = 0, rb = 0;
    if (y > 0) {
      int wa = wi - WPR;
      ca = occ[wa]; la = wx ? occ[wa - 1] : 0u; ra = (wx < 15) ? occ[wa + 1] : 0u;
    }
    if (y < GRIDW - 1) {
      int wb = wi + WPR;
      cb = occ[wb]; lb = wx ? occ[wb - 1] : 0u; rb = (wx < 15) ? occ[wb + 1] : 0u;
    }
    uint64_t winA = ((uint64_t)ca << 1) | (la >> 31) | ((uint64_t)(ra & 1) << 33);
    uint64_t winC = ((uint64_t)w  << 1) | (lc >> 31) | ((uint64_t)(rc & 1) << 33);
    uint64_t winB = ((uint64_t)cb << 1) | (lb >> 31) | ((uint64_t)(rb & 1) << 33);
    int rbase = pre2[wi >> 1] + ((wi & 1) ? __popc(lc) : 0);  // wi odd => wx>=1
    uint32_t wrem = w; int r = rbase;
    while (wrem) {
      int b = __ffs(wrem) - 1; wrem &= wrem - 1;
      uint32_t v = (uint32_t)((winA >> b) & 7) |
                   ((uint32_t)((winC >> b) & 7) << 3) |
                   ((uint32_t)((winB >> b) & 7) << 6);
      if (__popc(v) >= 5) {
        labels[r] = (uint16_t)r;
        atomicOr(&coreflag[r >> 5], 1u << (r & 31));
      }
      r++;
    }
  }
  __syncthreads();

  // ---- P5 merge: union core-core edges (E, SW, S, SE forward neighbors) ----
  for (int wi = tid; wi < NWORDS; wi += NTHREADS) {
    uint32_t w = occ[wi];
    if (!w) continue;
    int y = wi >> 4, wx = wi & 15;
    uint32_t lc = wx ? occ[wi - 1] : 0u;
    uint32_t rc = (wx < 15) ? occ[wi + 1] : 0u;
    int rbase = pre2[wi >> 1] + ((wi & 1) ? __popc(lc) : 0);
    bool hasB = (y < GRIDW - 1);
    uint32_t bel = 0, belL = 0, belR = 0; int rB = 0;
    if (hasB) {
      int wb = wi + WPR;
      bel = occ[wb];
      belL = wx ? occ[wb - 1] : 0u;
      belR = (wx < 15) ? occ[wb + 1] : 0u;
      rB = pre2[wb >> 1] + ((wb & 1) ? __popc(belL) : 0);  // wb odd => wx>=1
    }
    uint32_t wrem = w; int r = rbase;
    while (wrem) {
      int b = __ffs(wrem) - 1; wrem &= wrem - 1;
      if ((coreflag[r >> 5] >> (r & 31)) & 1) {
        bool eocc = (b < 31) ? ((w >> (b + 1)) & 1) : (rc & 1);
        if (eocc) {  // east neighbor, rank is always r+1
          int nr = r + 1;
          if ((coreflag[nr >> 5] >> (nr & 31)) & 1) unite16(labels, r, nr);
        }
        if (hasB) {
          if ((bel >> b) & 1) {  // S
            int nr = rB + __popc(bel & ((1u << b) - 1u));
            if ((coreflag[nr >> 5] >> (nr & 31)) & 1) unite16(labels, r, nr);
          }
          bool seocc = (b < 31) ? ((bel >> (b + 1)) & 1) : (belR & 1);
          if (seocc) {  // SE
            int nr = (b < 31) ? (rB + __popc(bel & ((2u << b) - 1u)))
                              : (rB + __popc(bel));
            if ((coreflag[nr >> 5] >> (nr & 31)) & 1) unite16(labels, r, nr);
          }
          bool swocc = (b > 0) ? ((bel >> (b - 1)) & 1) : ((belL >> 31) & 1);
          if (swocc) {  // SW
            int nr = (b > 0) ? (rB + __popc(bel & ((1u << (b - 1)) - 1u)))
                             : (rB - 1);
            if ((coreflag[nr >> 5] >> (nr & 31)) & 1) unite16(labels, r, nr);
          }
        }
      }
      r++;
    }
  }
  __syncthreads();

  // ---- P6 compress cores to roots + root bitmap ----
  for (int r = tid; r < M; r += NTHREADS) {
    if ((coreflag[r >> 5] >> (r & 31)) & 1) {
      int rt = find16(labels, r);
      labels[r] = (uint16_t)rt;
      if (rt == r) atomicOr(&rootbm[r >> 5], 1u << (r & 31));
    }
  }
  __syncthreads();

  // ---- P7 border attach: non-core occupied -> min root of core neighbors ----
  for (int wi = tid; wi < NWORDS; wi += NTHREADS) {
    uint32_t w = occ[wi];
    if (!w) continue;
    int y = wi >> 4, wx = wi & 15;
    uint32_t lc = wx ? occ[wi - 1] : 0u;
    uint32_t rc = (wx < 15) ? occ[wi + 1] : 0u;
    int rbase = pre2[wi >> 1] + ((wi & 1) ? __popc(lc) : 0);
    bool hasA = (y > 0), hasB = (y < GRIDW - 1);
    uint32_t ab = 0, abL = 0, abR = 0; int rA = 0;
    if (hasA) {
      int wa = wi - WPR;
      ab = occ[wa]; abL = wx ? occ[wa - 1] : 0u; abR = (wx < 15) ? occ[wa + 1] : 0u;
      rA = pre2[wa >> 1] + ((wa & 1) ? __popc(abL) : 0);
    }
    uint32_t bel = 0, belL = 0, belR = 0; int rB = 0;
    if (hasB) {
      int wb = wi + WPR;
      bel = occ[wb]; belL = wx ? occ[wb - 1] : 0u; belR = (wx < 15) ? occ[wb + 1] : 0u;
      rB = pre2[wb >> 1] + ((wb & 1) ? __popc(belL) : 0);
    }
    uint32_t wrem = w; int r = rbase;
    while (wrem) {
      int b = __ffs(wrem) - 1; wrem &= wrem - 1;
      if (!((coreflag[r >> 5] >> (r & 31)) & 1)) {
        int m = BIGL;
        bool wocc = (b > 0) ? ((w >> (b - 1)) & 1) : ((lc >> 31) & 1);
        if (wocc) {
          int nr = r - 1;
          if ((coreflag[nr >> 5] >> (nr & 31)) & 1) { int lv = labels[nr]; if (lv < m) m = lv; }
        }
        bool eocc = (b < 31) ? ((w >> (b + 1)) & 1) : (rc & 1);
        if (eocc) {
          int nr = r + 1;
          if ((coreflag[nr >> 5] >> (nr & 31)) & 1) { int lv = labels[nr]; if (lv < m) m = lv; }
        }
        if (hasA) {
          if ((ab >> b) & 1) {
            int nr = rA + __popc(ab & ((1u << b) - 1u));
            if ((coreflag[nr >> 5] >> (nr & 31)) & 1) { int lv = labels[nr]; if (lv < m) m = lv; }
          }
          bool neocc = (b < 31) ? ((ab >> (b + 1)) & 1) : (abR & 1);
          if (neocc) {
            int nr = (b < 31) ? (rA + __popc(ab & ((2u << b) - 1u))) : (rA + __popc(ab));
            if ((coreflag[nr >> 5] >> (nr & 31)) & 1) { int lv = labels[nr]; if (lv < m) m = lv; }
          }
          bool nwocc = (b > 0) ? ((ab >> (b - 1)) & 1) : ((abL >> 31) & 1);
          if (nwocc) {
            int nr = (b > 0) ? (rA + __popc(ab & ((1u << (b - 1)) - 1u))) : (rA - 1);
            if ((coreflag[nr >> 5] >> (nr & 31)) & 1) { int lv = labels[nr]; if (lv < m) m = lv; }
          }
        }
        if (hasB) {
          if ((bel >> b) & 1) {
            int nr = rB + __popc(bel & ((1u << b) - 1u));
            if ((coreflag[nr >> 5] >> (nr & 31)) & 1) { int lv = labels[nr]; if (lv < m) m = lv; }
          }
          bool seocc = (b < 31) ? ((bel >> (b + 1)) & 1) : (belR & 1);
          if (seocc) {
            int nr = (b < 31) ? (rB + __popc(bel & ((2u << b) - 1u))) : (rB + __popc(bel));
            if ((coreflag[nr >> 5] >> (nr & 31)) & 1) { int lv = labels[nr]; if (lv < m) m = lv; }
          }
          bool swocc = (b > 0) ? ((bel >> (b - 1)) & 1) : ((belL >> 31) & 1);
          if (swocc) {
            int nr = (b > 0) ? (rB + __popc(bel & ((1u << (b - 1)) - 1u))) : (rB - 1);
            if ((coreflag[nr >> 5] >> (nr & 31)) & 1) { int lv = labels[nr]; if (lv < m) m = lv; }
          }
        }
        labels[r] = (uint16_t)m;  // BIGL => noise
      }
      r++;
    }
  }
  __syncthreads();

  // ---- P8 dense root numbering (exclusive prefix over rootbm popcounts) ----
  {
    uint32_t v = (tid < 256) ? __popc(rootbm[tid]) : 0u;
    scanbuf[tid] = v;
    __syncthreads();
    for (int off = 1; off < 256; off <<= 1) {
      uint32_t x = scanbuf[tid];
      uint32_t a = (tid >= off && tid < 256) ? scanbuf[tid - off] : 0u;
      __syncthreads();
      scanbuf[tid] = x + a;
      __syncthreads();
    }
    if (tid < 256) rootpre[tid] = (uint16_t)(scanbuf[tid] - v);
  }
  __syncthreads();

  // ---- P9 per-cluster voxel counts (reuse occ as cnt; occ is dead now) ----
  uint32_t* cnt = occ;
  for (int i = tid; i < 8192; i += NTHREADS) cnt[i] = 0u;
  __syncthreads();
  for (int r = tid; r < M; r += NTHREADS) {
    int l = labels[r];
    if (l != BIGL) atomicAdd(&cnt[l], 1u);
  }
  __syncthreads();
  for (int r = tid; r < M; r += NTHREADS) {
    if (((rootbm[r >> 5] >> (r & 31)) & 1) && cnt[r] >= 20u)
      atomicOr(&keepbm[r >> 5], 1u << (r & 31));
  }
  __syncthreads();

  // ---- P10 scatter labels to points ----
  for (int k = 0; k < 8; k++) {
    int i = k * NTHREADS + tid;
    if (i >= npts) continue;
    int l = labels[myRank[k]];
    float o = -1.0f;
    if (l != BIGL && ((keepbm[l >> 5] >> (l & 31)) & 1)) {
      int d = rootpre[l >> 5] + __popc(rootbm[l >> 5] & ((1u << (l & 31)) - 1u));
      o = (float)d;
      atomicMax(&sMaxd, d);
    }
    out[i] = o;
  }
  __syncthreads();
  if (tid == 0) out[npts] = (float)(sMaxd + 1);
}

extern "C" void kernel_launch(void* const* d_in, const int* in_sizes, int n_in,
                              void* d_out, int out_size, void* d_ws, size_t ws_size,
                              hipStream_t stream) {
  const float* pts = (const float*)d_in[0];
  int npts = in_sizes[0] / 5;  // points are (N,5) float32
  cluster_kernel<<<1, NTHREADS, 0, stream>>>(pts, (float*)d_out, npts);
}

// Round 3
// 159.092 us; speedup vs baseline: 4.5079x; 1.2553x over previous
//
#include <hip/hip_runtime.h>
#include <stdint.h>

// DBSCAN-on-voxel-grid, exact port of the JAX reference for batch_size==1.
// Grid 512x512, eps=1.5 => 8-connected adjacency, min_samples=5 (voxels,
// incl. self), clusters with <20 voxels dropped. Single block, 1024 threads.
// R3: bit-sliced SWAR 3x3 counts -> per-word core masks (no per-rank coreflag,
// no per-bit dependent LDS chains); wave-shuffle scans.

#define GRIDW 512
#define WPR 16        // bitmap words per row
#define NWORDS 8192   // 512*512/32
#define NTHREADS 1024
#define BIGL 0xFFFF

__device__ __forceinline__ uint16_t cas16(uint16_t* p, uint16_t cmp, uint16_t val) {
  uint32_t* w = (uint32_t*)((uintptr_t)p & ~(uintptr_t)3);
  unsigned sh = ((uintptr_t)p & 2) ? 16u : 0u;
  uint32_t msk = 0xFFFFu << sh;
  uint32_t old = *(volatile uint32_t*)w;
  for (;;) {
    uint16_t cur = (uint16_t)((old >> sh) & 0xFFFFu);
    if (cur != cmp) return cur;
    uint32_t nv = (old & ~msk) | ((uint32_t)val << sh);
    uint32_t prev = atomicCAS(w, old, nv);
    if (prev == old) return cmp;
    old = prev;
  }
}

__device__ __forceinline__ int find16(uint16_t* L, int x) {
  volatile uint16_t* vl = (volatile uint16_t*)L;
  int p = vl[x];
  while (p != x) { x = p; p = vl[x]; }
  return x;
}

// link larger root under smaller => final root == min core rank of component
__device__ __forceinline__ void unite16(uint16_t* L, int a, int b) {
  for (;;) {
    a = find16(L, a);
    b = find16(L, b);
    if (a == b) return;
    int lo = a < b ? a : b;
    int hi = a ^ b ^ lo;
    if (cas16(&L[hi], (uint16_t)hi, (uint16_t)lo) == (uint16_t)hi) return;
    a = lo; b = hi;
  }
}

// per-position horizontal (west+self+east) 2-bit counts for one row of 32 cells
__device__ __forceinline__ void hsum(uint32_t l, uint32_t c, uint32_t r,
                                     uint32_t& h0, uint32_t& h1) {
  uint32_t Wb = (c << 1) | (l >> 31);
  uint32_t Eb = (c >> 1) | (r << 31);
  h0 = Wb ^ c ^ Eb;
  h1 = (Wb & c) | (Eb & (Wb ^ c));
}

// per-position (sum of three 2-bit row counts) >= 5  (bit-sliced adders)
__device__ __forceinline__ uint32_t ge5(uint32_t a0, uint32_t a1, uint32_t b0,
                                        uint32_t b1, uint32_t c0, uint32_t c1) {
  uint32_t u0 = a0 ^ b0, cy = a0 & b0;
  uint32_t t = a1 ^ b1;
  uint32_t u1 = t ^ cy;
  uint32_t u2 = (a1 & b1) | (cy & t);
  uint32_t v0 = u0 ^ c0, k0 = u0 & c0;
  uint32_t t2 = u1 ^ c1;
  uint32_t v1 = t2 ^ k0;
  uint32_t k1 = (u1 & c1) | (k0 & t2);
  uint32_t v2 = u2 ^ k1;
  uint32_t v3 = u2 & k1;
  return v3 | (v2 & (v1 | v0));  // count in {5..9}
}

// core status (0/1) of bit0 of the word RIGHT of the (cU,rU)/(cC,rC)/(cD,rD) rows
__device__ __forceinline__ uint32_t coreRbit(uint32_t cU, uint32_t rU, uint32_t cC,
                                             uint32_t rC, uint32_t cD, uint32_t rD) {
  if (!(rC & 1u)) return 0u;
  int n = __popc((cU >> 31) | ((rU & 3u) << 1)) +
          __popc((cC >> 31) | ((rC & 3u) << 1)) +
          __popc((cD >> 31) | ((rD & 3u) << 1));
  return n >= 5 ? 1u : 0u;
}

// core status (0/1) of bit31 of the word LEFT of the rows
__device__ __forceinline__ uint32_t coreLbit(uint32_t cU, uint32_t lU, uint32_t cC,
                                             uint32_t lC, uint32_t cD, uint32_t lD) {
  if (!(lC >> 31)) return 0u;
  int n = __popc(((lU >> 30) & 3u) | ((cU & 1u) << 2)) +
          __popc(((lC >> 30) & 3u) | ((cC & 1u) << 2)) +
          __popc(((lD >> 30) & 3u) | ((cD & 1u) << 2));
  return n >= 5 ? 1u : 0u;
}

__global__ __launch_bounds__(NTHREADS) void cluster_kernel(
    const float* __restrict__ pts, float* __restrict__ out, int npts) {
  __shared__ uint32_t occ[NWORDS];    // 32 KB bitmap; reused as cnt[] in P9
  __shared__ uint16_t pre2[4096];     // 8 KB: excl. voxel prefix per 64-cell pair
  __shared__ uint16_t labels[8192];   // 16 KB
  __shared__ uint32_t rootbm[256];
  __shared__ uint32_t keepbm[256];
  __shared__ uint16_t rootpre[256];
  __shared__ uint32_t wsum[16];
  __shared__ int sMaxd, sM;

  const int tid = threadIdx.x;
  const int lane = tid & 63, wv = tid >> 6;

  // ---- P0 init ----
  for (int i = tid; i < NWORDS; i += NTHREADS) occ[i] = 0u;
  for (int i = tid; i < 4096; i += NTHREADS) ((uint32_t*)labels)[i] = 0xFFFFFFFFu;
  if (tid < 256) { rootbm[tid] = 0u; keepbm[tid] = 0u; }
  if (tid == 0) sMaxd = -1;
  __syncthreads();

  // ---- P1 voxelize ----
  int myCell[8];
#pragma unroll
  for (int k = 0; k < 8; k++) {
    int i = k * NTHREADS + tid;
    int cell = -1;
    if (i < npts) {
      float x = pts[i * 5 + 1];
      float y = pts[i * 5 + 2];
      int cx = (int)floorf((x - (-51.2f)) / 0.2f);  // identical f32 ops to jnp
      int cy = (int)floorf((y - (-51.2f)) / 0.2f);
      cx = min(max(cx, 0), GRIDW - 1);
      cy = min(max(cy, 0), GRIDW - 1);
      cell = cy * GRIDW + cx;
      atomicOr(&occ[cell >> 5], 1u << (cell & 31));
    }
    myCell[k] = cell;
  }
  __syncthreads();

  // ---- P2 voxel-rank prefix (wave-shuffle scan, 3 barriers) ----
  {
    uint32_t s[4], tot = 0;
#pragma unroll
    for (int j = 0; j < 4; j++) {
      int g = tid * 4 + j;
      s[j] = __popc(occ[2 * g]) + __popc(occ[2 * g + 1]);
      tot += s[j];
    }
    uint32_t inc = tot;
    for (int d = 1; d < 64; d <<= 1) { uint32_t t = __shfl_up(inc, d); if (lane >= d) inc += t; }
    if (lane == 63) wsum[wv] = inc;
    __syncthreads();
    if (tid < 16) {
      uint32_t u = wsum[tid];
      for (int d = 1; d < 16; d <<= 1) { uint32_t t = __shfl_up(u, d); if (tid >= d) u += t; }
      wsum[tid] = u;
    }
    __syncthreads();
    uint32_t woff = wv ? wsum[wv - 1] : 0u;
    uint32_t excl = woff + inc - tot;
#pragma unroll
    for (int j = 0; j < 4; j++) { pre2[tid * 4 + j] = (uint16_t)excl; excl += s[j]; }
    if (tid == NTHREADS - 1) sM = (int)(woff + inc);
  }
  __syncthreads();
  const int M = sM;

  // ---- P3 per-point ranks (registers) ----
  int myRank[8];
#pragma unroll
  for (int k = 0; k < 8; k++) {
    int cell = myCell[k];
    int r = -1;
    if (cell >= 0) {
      int wi = cell >> 5;
      r = pre2[cell >> 6];
      if (wi & 1) r += __popc(occ[wi - 1]);
      r += __popc(occ[wi] & ((1u << (cell & 31)) - 1u));
    }
    myRank[k] = r;
  }

  // ---- P4 core labels init (bit-sliced core mask per word) ----
  for (int wi = tid; wi < NWORDS; wi += NTHREADS) {
    uint32_t cB = occ[wi];
    if (!cB) continue;
    int y = wi >> 4, wx = wi & 15;
    uint32_t lB = wx ? occ[wi - 1] : 0u;
    uint32_t rBw = (wx < 15) ? occ[wi + 1] : 0u;
    uint32_t cA = 0, lA = 0, rAw = 0, cC = 0, lC = 0, rCw = 0;
    if (y > 0) { int wa = wi - WPR; cA = occ[wa]; lA = wx ? occ[wa - 1] : 0u; rAw = (wx < 15) ? occ[wa + 1] : 0u; }
    if (y < GRIDW - 1) { int wc = wi + WPR; cC = occ[wc]; lC = wx ? occ[wc - 1] : 0u; rCw = (wx < 15) ? occ[wc + 1] : 0u; }
    uint32_t a0, a1, b0, b1, c0, c1;
    hsum(lA, cA, rAw, a0, a1); hsum(lB, cB, rBw, b0, b1); hsum(lC, cC, rCw, c0, c1);
    uint32_t cw = ge5(a0, a1, b0, b1, c0, c1) & cB;
    if (!cw) continue;
    int rbase = pre2[wi >> 1] + ((wi & 1) ? __popc(lB) : 0);
    while (cw) {
      int b = __ffs(cw) - 1; cw &= cw - 1;
      int r = rbase + __popc(cB & ((1u << b) - 1u));
      labels[r] = (uint16_t)r;
    }
  }
  __syncthreads();

  // ---- P5 merge: union core-core edges (E, S, SE, SW) via mask tests ----
  for (int wi = tid; wi < NWORDS; wi += NTHREADS) {
    uint32_t cB = occ[wi];
    if (!cB) continue;
    int y = wi >> 4, wx = wi & 15;
    uint32_t lB = wx ? occ[wi - 1] : 0u;
    uint32_t rBw = (wx < 15) ? occ[wi + 1] : 0u;
    uint32_t cA = 0, lA = 0, rAw = 0, cC = 0, lC = 0, rCw = 0, cD = 0, lD = 0, rDw = 0;
    if (y > 0) { int wa = wi - WPR; cA = occ[wa]; lA = wx ? occ[wa - 1] : 0u; rAw = (wx < 15) ? occ[wa + 1] : 0u; }
    if (y < GRIDW - 1) { int wc = wi + WPR; cC = occ[wc]; lC = wx ? occ[wc - 1] : 0u; rCw = (wx < 15) ? occ[wc + 1] : 0u; }
    if (y < GRIDW - 2) { int wd = wi + 2 * WPR; cD = occ[wd]; lD = wx ? occ[wd - 1] : 0u; rDw = (wx < 15) ? occ[wd + 1] : 0u; }
    uint32_t hA0, hA1, hB0, hB1, hC0, hC1, hD0, hD1;
    hsum(lA, cA, rAw, hA0, hA1); hsum(lB, cB, rBw, hB0, hB1);
    hsum(lC, cC, rCw, hC0, hC1); hsum(lD, cD, rDw, hD0, hD1);
    uint32_t cw0 = ge5(hA0, hA1, hB0, hB1, hC0, hC1) & cB;
    if (!cw0) continue;
    uint32_t cw1 = ge5(hB0, hB1, hC0, hC1, hD0, hD1) & cC;
    uint32_t eR = coreRbit(cA, rAw, cB, rBw, cC, rCw);
    uint32_t seR = coreRbit(cB, rBw, cC, rCw, cD, rDw);
    uint32_t swL = coreLbit(cB, lB, cC, lC, cD, lD);
    uint32_t ec = cw0 & ((cw0 >> 1) | (eR << 31));
    uint32_t sc = cw0 & cw1;
    uint32_t sec = cw0 & ((cw1 >> 1) | (seR << 31));
    uint32_t swc = cw0 & ((cw1 << 1) | swL);
    uint32_t um = ec | sc | sec | swc;
    if (!um) continue;
    int rbase = pre2[wi >> 1] + ((wi & 1) ? __popc(lB) : 0);
    int rBlo = 0;
    if (sc | sec | swc) { int wc = wi + WPR; rBlo = pre2[wc >> 1] + ((wc & 1) ? __popc(lC) : 0); }
    while (um) {
      int b = __ffs(um) - 1; um &= um - 1;
      int r = rbase + __popc(cB & ((1u << b) - 1u));
      if ((ec >> b) & 1)  unite16(labels, r, (b < 31) ? r + 1 : rbase + __popc(cB));
      if ((sc >> b) & 1)  unite16(labels, r, rBlo + __popc(cC & ((1u << b) - 1u)));
      if ((sec >> b) & 1) unite16(labels, r, (b < 31) ? rBlo + __popc(cC & ((2u << b) - 1u)) : rBlo + __popc(cC));
      if ((swc >> b) & 1) unite16(labels, r, (b > 0) ? rBlo + __popc(cC & ((1u << (b - 1)) - 1u)) : rBlo - 1);
    }
  }
  __syncthreads();

  // ---- P6 compress cores to roots (core <=> labels[r] != BIG here) ----
  for (int r = tid; r < M; r += NTHREADS) {
    if (labels[r] != (uint16_t)BIGL) {
      int rt = find16(labels, r);
      labels[r] = (uint16_t)rt;
      if (rt == r) atomicOr(&rootbm[r >> 5], 1u << (r & 31));
    }
  }
  __syncthreads();

  // ---- P7 border attach: min compressed root among core neighbors ----
  for (int wi = tid; wi < NWORDS; wi += NTHREADS) {
    uint32_t cB = occ[wi];
    if (!cB) continue;
    int y = wi >> 4, wx = wi & 15;
    uint32_t lB = wx ? occ[wi - 1] : 0u;
    uint32_t rBw = (wx < 15) ? occ[wi + 1] : 0u;
    uint32_t cZ = 0, lZ = 0, rZw = 0, cA = 0, lA = 0, rAw = 0;
    uint32_t cC = 0, lC = 0, rCw = 0, cD = 0, lD = 0, rDw = 0;
    if (y > 1) { int wz = wi - 2 * WPR; cZ = occ[wz]; lZ = wx ? occ[wz - 1] : 0u; rZw = (wx < 15) ? occ[wz + 1] : 0u; }
    if (y > 0) { int wa = wi - WPR; cA = occ[wa]; lA = wx ? occ[wa - 1] : 0u; rAw = (wx < 15) ? occ[wa + 1] : 0u; }
    if (y < GRIDW - 1) { int wc = wi + WPR; cC = occ[wc]; lC = wx ? occ[wc - 1] : 0u; rCw = (wx < 15) ? occ[wc + 1] : 0u; }
    if (y < GRIDW - 2) { int wd = wi + 2 * WPR; cD = occ[wd]; lD = wx ? occ[wd - 1] : 0u; rDw = (wx < 15) ? occ[wd + 1] : 0u; }
    uint32_t hZ0, hZ1, hA0, hA1, hB0, hB1, hC0, hC1, hD0, hD1;
    hsum(lZ, cZ, rZw, hZ0, hZ1); hsum(lA, cA, rAw, hA0, hA1); hsum(lB, cB, rBw, hB0, hB1);
    hsum(lC, cC, rCw, hC0, hC1); hsum(lD, cD, rDw, hD0, hD1);
    uint32_t cw0 = ge5(hA0, hA1, hB0, hB1, hC0, hC1) & cB;
    uint32_t nb = cB & ~cw0;
    if (!nb) continue;
    uint32_t cwm1 = ge5(hZ0, hZ1, hA0, hA1, hB0, hB1) & cA;
    uint32_t cw1 = ge5(hB0, hB1, hC0, hC1, hD0, hD1) & cC;
    uint32_t wL = coreLbit(cA, lA, cB, lB, cC, lC);
    uint32_t eR = coreRbit(cA, rAw, cB, rBw, cC, rCw);
    uint32_t nwL = coreLbit(cZ, lZ, cA, lA, cB, lB);
    uint32_t neR = coreRbit(cZ, rZw, cA, rAw, cB, rBw);
    uint32_t swL = coreLbit(cB, lB, cC, lC, cD, lD);
    uint32_t seR = coreRbit(cB, rBw, cC, rCw, cD, rDw);
    uint32_t Wc = (cw0 << 1) | wL;
    uint32_t Ec = (cw0 >> 1) | (eR << 31);
    uint32_t Nc = cwm1, Sc = cw1;
    uint32_t NWc = (cwm1 << 1) | nwL;
    uint32_t NEc = (cwm1 >> 1) | (neR << 31);
    uint32_t SWc = (cw1 << 1) | swL;
    uint32_t SEc = (cw1 >> 1) | (seR << 31);
    int rbase = pre2[wi >> 1] + ((wi & 1) ? __popc(lB) : 0);
    int rAlo = 0, rBlo = 0;
    if (y > 0) { int wa = wi - WPR; rAlo = pre2[wa >> 1] + ((wa & 1) ? __popc(lA) : 0); }
    if (y < GRIDW - 1) { int wc = wi + WPR; rBlo = pre2[wc >> 1] + ((wc & 1) ? __popc(lC) : 0); }
    while (nb) {
      int b = __ffs(nb) - 1; nb &= nb - 1;
      int r = rbase + __popc(cB & ((1u << b) - 1u));
      int m = BIGL, lv;
      if ((Wc >> b) & 1)  { lv = labels[(b > 0) ? r - 1 : rbase - 1]; m = lv < m ? lv : m; }
      if ((Ec >> b) & 1)  { lv = labels[(b < 31) ? r + 1 : rbase + __popc(cB)]; m = lv < m ? lv : m; }
      if ((Nc >> b) & 1)  { lv = labels[rAlo + __popc(cA & ((1u << b) - 1u))]; m = lv < m ? lv : m; }
      if ((NWc >> b) & 1) { lv = labels[(b > 0) ? rAlo + __popc(cA & ((1u << (b - 1)) - 1u)) : rAlo - 1]; m = lv < m ? lv : m; }
      if ((NEc >> b) & 1) { lv = labels[(b < 31) ? rAlo + __popc(cA & ((2u << b) - 1u)) : rAlo + __popc(cA)]; m = lv < m ? lv : m; }
      if ((Sc >> b) & 1)  { lv = labels[rBlo + __popc(cC & ((1u << b) - 1u))]; m = lv < m ? lv : m; }
      if ((SWc >> b) & 1) { lv = labels[(b > 0) ? rBlo + __popc(cC & ((1u << (b - 1)) - 1u)) : rBlo - 1]; m = lv < m ? lv : m; }
      if ((SEc >> b) & 1) { lv = labels[(b < 31) ? rBlo + __popc(cC & ((2u << b) - 1u)) : rBlo + __popc(cC)]; m = lv < m ? lv : m; }
      labels[r] = (uint16_t)m;  // BIGL => noise
    }
  }
  __syncthreads();

  // ---- P8 dense root numbering ----
  {
    uint32_t v = (tid < 256) ? __popc(rootbm[tid]) : 0u;
    uint32_t inc = v;
    for (int d = 1; d < 64; d <<= 1) { uint32_t t = __shfl_up(inc, d); if (lane >= d) inc += t; }
    if (tid < 256 && lane == 63) wsum[wv] = inc;
    __syncthreads();
    if (tid < 4) {
      uint32_t u = wsum[tid];
      for (int d = 1; d < 4; d <<= 1) { uint32_t t = __shfl_up(u, d); if (tid >= d) u += t; }
      wsum[tid] = u;
    }
    __syncthreads();
    if (tid < 256) rootpre[tid] = (uint16_t)((wv ? wsum[wv - 1] : 0u) + inc - v);
  }
  __syncthreads();

  // ---- P9 per-cluster voxel counts (reuse occ as cnt) + keep ----
  uint32_t* cnt = occ;
  for (int i = tid; i < 8192; i += NTHREADS) cnt[i] = 0u;
  __syncthreads();
  for (int r = tid; r < M; r += NTHREADS) {
    int l = labels[r];
    if (l != BIGL) atomicAdd(&cnt[l], 1u);
  }
  __syncthreads();
  for (int r = tid; r < M; r += NTHREADS) {
    if (((rootbm[r >> 5] >> (r & 31)) & 1) && cnt[r] >= 20u)
      atomicOr(&keepbm[r >> 5], 1u << (r & 31));
  }
  __syncthreads();

  // ---- P10 scatter to points ----
#pragma unroll
  for (int k = 0; k < 8; k++) {
    int i = k * NTHREADS + tid;
    if (i >= npts) continue;
    int l = labels[myRank[k]];
    float o = -1.0f;
    if (l != BIGL && ((keepbm[l >> 5] >> (l & 31)) & 1)) {
      int d = rootpre[l >> 5] + __popc(rootbm[l >> 5] & ((1u << (l & 31)) - 1u));
      o = (float)d;
      atomicMax(&sMaxd, d);
    }
    out[i] = o;
  }
  __syncthreads();
  if (tid == 0) out[npts] = (float)(sMaxd + 1);
}

extern "C" void kernel_launch(void* const* d_in, const int* in_sizes, int n_in,
                              void* d_out, int out_size, void* d_ws, size_t ws_size,
                              hipStream_t stream) {
  const float* pts = (const float*)d_in[0];
  int npts = in_sizes[0] / 5;  // points are (N,5) float32
  cluster_kernel<<<1, NTHREADS, 0, stream>>>(pts, (float*)d_out, npts);
}

// Round 4
// 138.677 us; speedup vs baseline: 5.1715x; 1.1472x over previous
//
#include <hip/hip_runtime.h>
#include <stdint.h>

// DBSCAN-on-voxel-grid, exact port of the JAX reference for batch_size==1.
// Grid 512x512, eps=1.5 => 8-connected adjacency, min_samples=5 (voxels,
// incl. self), clusters with <20 voxels dropped.
// R4: multi-CU pipeline of 8 graph-captured dispatches; state in d_ws (L2).
// Union-find runs on global memory with device-scope atomics (coherent
// across XCDs); plain loads of labels only read values that monotonically
// shorten paths, so staleness is benign.

#define GRIDW 512
#define WPR 16        // bitmap words per row
#define NWORDS 8192   // 512*512/32
#define NONE 0xFFFFFFFFu

// ---- ws layout (uint32 units) ----
#define OFF_OCC    0       // 8192: occupancy bitmap
#define OFF_CNT    8192    // 8192: per-root voxel counts
#define OFF_ROOTBM 16384   // 256
#define OFF_KEEPBM 16640   // 256
#define ZERO_WORDS 16896   // everything above must be zeroed
#define OFF_CM     16896   // 8192: core mask per word
#define OFF_LAB    25088   // 8192: union-find / final labels (by rank)
#define OFF_PRE    33280   // 8192: exclusive voxel-rank prefix per word
#define OFF_RPRE   41472   // 256: exclusive root-rank prefix per rootbm word
// total 41728 u32 = 166912 B

// per-position horizontal (west+self+east) 2-bit counts for a row of 32 cells
__device__ __forceinline__ void hsum(uint32_t l, uint32_t c, uint32_t r,
                                     uint32_t& h0, uint32_t& h1) {
  uint32_t Wb = (c << 1) | (l >> 31);
  uint32_t Eb = (c >> 1) | (r << 31);
  h0 = Wb ^ c ^ Eb;
  h1 = (Wb & c) | (Eb & (Wb ^ c));
}

// per-position (sum of three 2-bit row counts) >= 5 (bit-sliced adders)
__device__ __forceinline__ uint32_t ge5(uint32_t a0, uint32_t a1, uint32_t b0,
                                        uint32_t b1, uint32_t c0, uint32_t c1) {
  uint32_t u0 = a0 ^ b0, cy = a0 & b0;
  uint32_t t = a1 ^ b1;
  uint32_t u1 = t ^ cy;
  uint32_t u2 = (a1 & b1) | (cy & t);
  uint32_t v0 = u0 ^ c0, k0 = u0 & c0;
  uint32_t t2 = u1 ^ c1;
  uint32_t v1 = t2 ^ k0;
  uint32_t k1 = (u1 & c1) | (k0 & t2);
  uint32_t v2 = u2 ^ k1;
  uint32_t v3 = u2 & k1;
  return v3 | (v2 & (v1 | v0));  // count in {5..9}
}

__device__ __forceinline__ uint32_t aread(uint32_t* p) { return atomicOr(p, 0u); }

__device__ __forceinline__ uint32_t findr(uint32_t* L, uint32_t x) {
  uint32_t p = aread(&L[x]);
  while (p != x) { x = p; p = aread(&L[x]); }
  return x;
}

// link larger root under smaller => final root == min core rank of component
__device__ __forceinline__ void unite(uint32_t* L, uint32_t a, uint32_t b) {
  for (;;) {
    a = findr(L, a);
    b = findr(L, b);
    if (a == b) return;
    uint32_t lo = min(a, b), hi = max(a, b);
    if (atomicCAS(&L[hi], hi, lo) == hi) return;
    a = lo; b = hi;
  }
}

// K1: voxelize points -> occupancy bits (identical f32 ops to jnp)
__global__ void k_vox(const float* __restrict__ pts, uint32_t* __restrict__ ws,
                      int npts) {
  int i = blockIdx.x * 256 + threadIdx.x;
  if (i >= npts) return;
  float x = pts[i * 5 + 1];
  float y = pts[i * 5 + 2];
  int cx = (int)floorf((x - (-51.2f)) / 0.2f);
  int cy = (int)floorf((y - (-51.2f)) / 0.2f);
  cx = min(max(cx, 0), GRIDW - 1);
  cy = min(max(cy, 0), GRIDW - 1);
  int cell = cy * GRIDW + cx;
  atomicOr(&ws[OFF_OCC + (cell >> 5)], 1u << (cell & 31));
}

// K2: block 0 = voxel-rank prefix scan; blocks 1..32 = core masks + label init
__global__ void k_scan_cm(uint32_t* __restrict__ ws) {
  const uint32_t* occ = ws + OFF_OCC;
  int tid = threadIdx.x;
  if (blockIdx.x == 0) {
    __shared__ uint32_t wsum[4];
    int base = tid * 32;
    uint32_t s = 0;
    for (int j = 0; j < 32; j++) s += __popc(occ[base + j]);
    int lane = tid & 63, wv = tid >> 6;
    uint32_t inc = s;
    for (int d = 1; d < 64; d <<= 1) { uint32_t t = __shfl_up(inc, d); if (lane >= d) inc += t; }
    if (lane == 63) wsum[wv] = inc;
    __syncthreads();
    uint32_t woff = 0;
    for (int k = 0; k < wv; k++) woff += wsum[k];
    uint32_t excl = woff + inc - s;
    uint32_t* pre = ws + OFF_PRE;
    for (int j = 0; j < 32; j++) { pre[base + j] = excl; excl += __popc(occ[base + j]); }
  } else {
    int wi = (blockIdx.x - 1) * 256 + tid;
    ws[OFF_LAB + wi] = (uint32_t)wi;  // union-find self-init (by rank index)
    uint32_t cB = occ[wi];
    int y = wi >> 4, wx = wi & 15;
    uint32_t lB = wx ? occ[wi - 1] : 0u;
    uint32_t rB = (wx < 15) ? occ[wi + 1] : 0u;
    uint32_t cA = 0, lA = 0, rA = 0, cC = 0, lC = 0, rC = 0;
    if (y > 0) { int wa = wi - WPR; cA = occ[wa]; lA = wx ? occ[wa - 1] : 0u; rA = (wx < 15) ? occ[wa + 1] : 0u; }
    if (y < GRIDW - 1) { int wc = wi + WPR; cC = occ[wc]; lC = wx ? occ[wc - 1] : 0u; rC = (wx < 15) ? occ[wc + 1] : 0u; }
    uint32_t a0, a1, b0, b1, c0, c1;
    hsum(lA, cA, rA, a0, a1); hsum(lB, cB, rB, b0, b1); hsum(lC, cC, rC, c0, c1);
    ws[OFF_CM + wi] = ge5(a0, a1, b0, b1, c0, c1) & cB;
  }
}

// K3: union core-core edges (E, S, SE, SW forward neighbors)
__global__ void k_merge(uint32_t* __restrict__ ws) {
  int wi = blockIdx.x * 256 + threadIdx.x;
  const uint32_t* occ = ws + OFF_OCC;
  const uint32_t* cm = ws + OFF_CM;
  const uint32_t* pre = ws + OFF_PRE;
  uint32_t* lab = ws + OFF_LAB;
  uint32_t cw0 = cm[wi];
  if (!cw0) return;
  int y = wi >> 4, wx = wi & 15;
  bool hasS = y < GRIDW - 1;
  uint32_t cmS = hasS ? cm[wi + WPR] : 0u;
  uint32_t cmE = (wx < 15) ? cm[wi + 1] : 0u;
  uint32_t cmSE = (hasS && wx < 15) ? cm[wi + WPR + 1] : 0u;
  uint32_t cmSW = (hasS && wx > 0) ? cm[wi + WPR - 1] : 0u;
  uint32_t ec = cw0 & ((cw0 >> 1) | (cmE << 31));
  uint32_t sc = cw0 & cmS;
  uint32_t sec = cw0 & ((cmS >> 1) | (cmSE << 31));
  uint32_t swc = cw0 & ((cmS << 1) | (cmSW >> 31));
  uint32_t um = ec | sc | sec | swc;
  if (!um) return;
  uint32_t cB = occ[wi];
  int rbase = pre[wi];
  uint32_t occS = hasS ? occ[wi + WPR] : 0u;
  int rS = hasS ? (int)pre[wi + WPR] : 0;
  while (um) {
    int b = __ffs(um) - 1; um &= um - 1;
    int r = rbase + __popc(cB & ((1u << b) - 1u));
    if ((ec >> b) & 1)  unite(lab, r, (b < 31) ? r + 1 : (int)pre[wi + 1]);
    if ((sc >> b) & 1)  unite(lab, r, rS + __popc(occS & ((1u << b) - 1u)));
    if ((sec >> b) & 1) unite(lab, r, (b < 31) ? rS + __popc(occS & ((2u << b) - 1u)) : (int)pre[wi + WPR + 1]);
    if ((swc >> b) & 1) unite(lab, r, (b > 0) ? rS + __popc(occS & ((1u << (b - 1)) - 1u)) : rS - 1);
  }
}

// K4: compress core labels to roots + root bitmap
__global__ void k_compress(uint32_t* __restrict__ ws) {
  int wi = blockIdx.x * 256 + threadIdx.x;
  uint32_t cw = ws[OFF_CM + wi];
  if (!cw) return;
  uint32_t cB = ws[OFF_OCC + wi];
  int rbase = ws[OFF_PRE + wi];
  uint32_t* lab = ws + OFF_LAB;
  while (cw) {
    int b = __ffs(cw) - 1; cw &= cw - 1;
    int r = rbase + __popc(cB & ((1u << b) - 1u));
    uint32_t root = findr(lab, r);
    lab[r] = root;
    if (root == (uint32_t)r) atomicOr(&ws[OFF_ROOTBM + (r >> 5)], 1u << (r & 31));
  }
}

// K5: border attach (min root among 8 core neighbors) + voxel counts per root
__global__ void k_border(uint32_t* __restrict__ ws) {
  int wi = blockIdx.x * 256 + threadIdx.x;
  const uint32_t* occ = ws + OFF_OCC;
  const uint32_t* cm = ws + OFF_CM;
  const uint32_t* pre = ws + OFF_PRE;
  uint32_t* lab = ws + OFF_LAB;
  uint32_t* cnt = ws + OFF_CNT;
  uint32_t cB = occ[wi];
  if (!cB) return;
  uint32_t cw0 = cm[wi];
  int y = wi >> 4, wx = wi & 15;
  int rbase = pre[wi];
  uint32_t cc = cw0;
  while (cc) {  // count core voxels into their root
    int b = __ffs(cc) - 1; cc &= cc - 1;
    int r = rbase + __popc(cB & ((1u << b) - 1u));
    atomicAdd(&cnt[lab[r]], 1u);
  }
  uint32_t nb = cB & ~cw0;
  if (!nb) return;
  bool hasN = y > 0, hasS = y < GRIDW - 1;
  uint32_t cmN = hasN ? cm[wi - WPR] : 0u, cmS = hasS ? cm[wi + WPR] : 0u;
  uint32_t cmW = wx ? cm[wi - 1] : 0u, cmE = (wx < 15) ? cm[wi + 1] : 0u;
  uint32_t cmNW = (hasN && wx) ? cm[wi - WPR - 1] : 0u;
  uint32_t cmNE = (hasN && wx < 15) ? cm[wi - WPR + 1] : 0u;
  uint32_t cmSW = (hasS && wx) ? cm[wi + WPR - 1] : 0u;
  uint32_t cmSE = (hasS && wx < 15) ? cm[wi + WPR + 1] : 0u;
  uint32_t Wc = (cw0 << 1) | (cmW >> 31), Ec = (cw0 >> 1) | (cmE << 31);
  uint32_t Nc = cmN, Sc = cmS;
  uint32_t NWc = (cmN << 1) | (cmNW >> 31), NEc = (cmN >> 1) | (cmNE << 31);
  uint32_t SWc = (cmS << 1) | (cmSW >> 31), SEc = (cmS >> 1) | (cmSE << 31);
  uint32_t occN = hasN ? occ[wi - WPR] : 0u, occS = hasS ? occ[wi + WPR] : 0u;
  int rN = hasN ? (int)pre[wi - WPR] : 0, rS = hasS ? (int)pre[wi + WPR] : 0;
  while (nb) {
    int b = __ffs(nb) - 1; nb &= nb - 1;
    int r = rbase + __popc(cB & ((1u << b) - 1u));
    uint32_t m = NONE, lv;
    if ((Wc >> b) & 1)  { lv = lab[(b > 0) ? r - 1 : rbase - 1]; m = min(m, lv); }
    if ((Ec >> b) & 1)  { lv = lab[(b < 31) ? r + 1 : (int)pre[wi + 1]]; m = min(m, lv); }
    if ((Nc >> b) & 1)  { lv = lab[rN + __popc(occN & ((1u << b) - 1u))]; m = min(m, lv); }
    if ((NWc >> b) & 1) { lv = lab[(b > 0) ? rN + __popc(occN & ((1u << (b - 1)) - 1u)) : rN - 1]; m = min(m, lv); }
    if ((NEc >> b) & 1) { lv = lab[(b < 31) ? rN + __popc(occN & ((2u << b) - 1u)) : (int)pre[wi - WPR + 1]]; m = min(m, lv); }
    if ((Sc >> b) & 1)  { lv = lab[rS + __popc(occS & ((1u << b) - 1u))]; m = min(m, lv); }
    if ((SWc >> b) & 1) { lv = lab[(b > 0) ? rS + __popc(occS & ((1u << (b - 1)) - 1u)) : rS - 1]; m = min(m, lv); }
    if ((SEc >> b) & 1) { lv = lab[(b < 31) ? rS + __popc(occS & ((2u << b) - 1u)) : (int)pre[wi + WPR + 1]]; m = min(m, lv); }
    lab[r] = m;  // NONE => noise
    if (m != NONE) atomicAdd(&cnt[m], 1u);
  }
}

// K6: dense root numbering, keep filter (>=20 voxels), max kept id -> out[npts]
__global__ void k_finish(uint32_t* __restrict__ ws, float* __restrict__ out,
                         int npts) {
  int tid = threadIdx.x;
  __shared__ uint32_t wsum[4];
  __shared__ int smax;
  if (tid == 0) smax = -1;
  __syncthreads();
  uint32_t rb = ws[OFF_ROOTBM + tid];
  uint32_t v = __popc(rb);
  int lane = tid & 63, wv = tid >> 6;
  uint32_t inc = v;
  for (int d = 1; d < 64; d <<= 1) { uint32_t t = __shfl_up(inc, d); if (lane >= d) inc += t; }
  if (lane == 63) wsum[wv] = inc;
  __syncthreads();
  uint32_t woff = 0;
  for (int k = 0; k < wv; k++) woff += wsum[k];
  uint32_t excl = woff + inc - v;
  ws[OFF_RPRE + tid] = excl;
  uint32_t keep = 0;
  int mx = -1, d = (int)excl;
  while (rb) {
    int b = __ffs(rb) - 1; rb &= rb - 1;
    int r = tid * 32 + b;
    if (ws[OFF_CNT + r] >= 20u) { keep |= 1u << b; mx = d; }
    d++;
  }
  ws[OFF_KEEPBM + tid] = keep;
  if (mx >= 0) atomicMax(&smax, mx);
  __syncthreads();
  if (tid == 0) out[npts] = (float)(smax + 1);
}

// K7: scatter dense labels back to points
__global__ void k_scatter(const float* __restrict__ pts,
                          const uint32_t* __restrict__ ws,
                          float* __restrict__ out, int npts) {
  int i = blockIdx.x * 256 + threadIdx.x;
  if (i >= npts) return;
  float x = pts[i * 5 + 1];
  float y = pts[i * 5 + 2];
  int cx = (int)floorf((x - (-51.2f)) / 0.2f);  // identical math to k_vox
  int cy = (int)floorf((y - (-51.2f)) / 0.2f);
  cx = min(max(cx, 0), GRIDW - 1);
  cy = min(max(cy, 0), GRIDW - 1);
  int cell = cy * GRIDW + cx;
  int wi = cell >> 5;
  int r = ws[OFF_PRE + wi] + __popc(ws[OFF_OCC + wi] & ((1u << (cell & 31)) - 1u));
  uint32_t l = ws[OFF_LAB + r];
  float o = -1.0f;
  if (l != NONE && ((ws[OFF_KEEPBM + (l >> 5)] >> (l & 31)) & 1)) {
    int dnum = ws[OFF_RPRE + (l >> 5)] +
               __popc(ws[OFF_ROOTBM + (l >> 5)] & ((1u << (l & 31)) - 1u));
    o = (float)dnum;
  }
  out[i] = o;
}

extern "C" void kernel_launch(void* const* d_in, const int* in_sizes, int n_in,
                              void* d_out, int out_size, void* d_ws, size_t ws_size,
                              hipStream_t stream) {
  const float* pts = (const float*)d_in[0];
  int npts = in_sizes[0] / 5;  // points are (N,5) float32
  uint32_t* ws = (uint32_t*)d_ws;
  float* out = (float*)d_out;
  int pblocks = (npts + 255) / 256;
  hipMemsetAsync(d_ws, 0, ZERO_WORDS * 4, stream);
  k_vox<<<pblocks, 256, 0, stream>>>(pts, ws, npts);
  k_scan_cm<<<33, 256, 0, stream>>>(ws);
  k_merge<<<32, 256, 0, stream>>>(ws);
  k_compress<<<32, 256, 0, stream>>>(ws);
  k_border<<<32, 256, 0, stream>>>(ws);
  k_finish<<<1, 256, 0, stream>>>(ws, out, npts);
  k_scatter<<<pblocks, 256, 0, stream>>>(pts, ws, out, npts);
}

// Round 6
// 96.387 us; speedup vs baseline: 7.4405x; 1.4388x over previous
//
#include <hip/hip_runtime.h>
#include <stdint.h>

// DBSCAN-on-voxel-grid, exact port of the JAX reference for batch_size==1.
// Grid 512x512, eps=1.5 => 8-connected adjacency, min_samples=5 (voxels,
// incl. self), clusters with <20 voxels dropped.
// R6 = R5 + fixed lock-free path compression (links must only DECREASE;
// unguarded CAS could write an upward link -> cycle -> hang, the likely
// cause of R5's bench failure).

#define GRIDW 512
#define WPR 16        // bitmap words per row
#define NWORDS 8192   // 512*512/32
#define NCELLS 262144
#define NONE 0xFFFFFFFFu

// ---- ws layout (uint32 units) ----
#define OFF_OCC    0       // 8192: occupancy bitmap (zeroed by memset)
#define OFF_CNT    8192    // 8192: per-root voxel counts (zeroed in k_scan_cm)
#define OFF_ROOTBM 16384   // 256 (zeroed in k_scan_cm)
#define OFF_KEEPBM 16640   // 256 (zeroed in k_scan_cm)
#define OFF_CM     16896   // 8192: core mask per word
#define OFF_LAB    25088   // 8192: union-find / final labels (by rank)
#define OFF_PRE    33280   // 8192: exclusive voxel-rank prefix per word
#define OFF_RPRE   41472   // 256: exclusive root-rank prefix per rootbm word

// per-position horizontal (west+self+east) 2-bit counts for a row of 32 cells
__device__ __forceinline__ void hsum(uint32_t l, uint32_t c, uint32_t r,
                                     uint32_t& h0, uint32_t& h1) {
  uint32_t Wb = (c << 1) | (l >> 31);
  uint32_t Eb = (c >> 1) | (r << 31);
  h0 = Wb ^ c ^ Eb;
  h1 = (Wb & c) | (Eb & (Wb ^ c));
}

// per-position (sum of three 2-bit row counts) >= 5 (bit-sliced adders)
__device__ __forceinline__ uint32_t ge5(uint32_t a0, uint32_t a1, uint32_t b0,
                                        uint32_t b1, uint32_t c0, uint32_t c1) {
  uint32_t u0 = a0 ^ b0, cy = a0 & b0;
  uint32_t t = a1 ^ b1;
  uint32_t u1 = t ^ cy;
  uint32_t u2 = (a1 & b1) | (cy & t);
  uint32_t v0 = u0 ^ c0, k0 = u0 & c0;
  uint32_t t2 = u1 ^ c1;
  uint32_t v1 = t2 ^ k0;
  uint32_t k1 = (u1 & c1) | (k0 & t2);
  uint32_t v2 = u2 ^ k1;
  uint32_t v3 = u2 & k1;
  return v3 | (v2 & (v1 | v0));  // count in {5..9}
}

__device__ __forceinline__ uint32_t aread(uint32_t* p) {
  return __hip_atomic_load(p, __ATOMIC_RELAXED, __HIP_MEMORY_SCOPE_AGENT);
}

// find root with guarded path compression: links are only ever LOWERED
// (write r into L[x] only while r < current link), preserving the
// monotone-decreasing invariant => no cycles, guaranteed termination.
__device__ __forceinline__ uint32_t findc(uint32_t* L, uint32_t x) {
  uint32_t r = x, p = aread(&L[r]);
  while (p != r) { r = p; p = aread(&L[r]); }
  while (x > r) {
    uint32_t nx = aread(&L[x]);
    if (nx <= r) break;          // someone already lowered it at least as far
    atomicCAS(&L[x], nx, r);     // best effort, only writes a smaller value
    x = nx;
  }
  return r;
}

// link larger root under smaller => final root == min core rank of component
__device__ __forceinline__ void unite(uint32_t* L, uint32_t a, uint32_t b) {
  for (;;) {
    a = findc(L, a);
    b = findc(L, b);
    if (a == b) return;
    uint32_t lo = min(a, b), hi = max(a, b);
    if (atomicCAS(&L[hi], hi, lo) == hi) return;  // hi still root => linked
    a = lo; b = hi;
  }
}

// K1: voxelize points -> occupancy bits (identical f32 ops to jnp)
__global__ void k_vox(const float* __restrict__ pts, uint32_t* __restrict__ ws,
                      int npts) {
  int i = blockIdx.x * 256 + threadIdx.x;
  if (i >= npts) return;
  float x = pts[i * 5 + 1];
  float y = pts[i * 5 + 2];
  int cx = (int)floorf((x - (-51.2f)) / 0.2f);
  int cy = (int)floorf((y - (-51.2f)) / 0.2f);
  cx = min(max(cx, 0), GRIDW - 1);
  cy = min(max(cy, 0), GRIDW - 1);
  int cell = cy * GRIDW + cx;
  atomicOr(&ws[OFF_OCC + (cell >> 5)], 1u << (cell & 31));
}

// K2: block 0 = voxel-rank prefix + zero rootbm/keepbm;
//     blocks 1..32 = core masks + label init + zero cnt
__global__ void k_scan_cm(uint32_t* __restrict__ ws) {
  const uint32_t* occ = ws + OFF_OCC;
  int tid = threadIdx.x;
  if (blockIdx.x == 0) {
    __shared__ uint32_t wsum[4];
    ws[OFF_ROOTBM + tid] = 0u;
    ws[OFF_KEEPBM + tid] = 0u;
    int base = tid * 32;
    uint32_t s = 0;
    for (int j = 0; j < 32; j++) s += __popc(occ[base + j]);
    int lane = tid & 63, wv = tid >> 6;
    uint32_t inc = s;
    for (int d = 1; d < 64; d <<= 1) { uint32_t t = __shfl_up(inc, d); if (lane >= d) inc += t; }
    if (lane == 63) wsum[wv] = inc;
    __syncthreads();
    uint32_t woff = 0;
    for (int k = 0; k < wv; k++) woff += wsum[k];
    uint32_t excl = woff + inc - s;
    uint32_t* pre = ws + OFF_PRE;
    for (int j = 0; j < 32; j++) { pre[base + j] = excl; excl += __popc(occ[base + j]); }
  } else {
    int wi = (blockIdx.x - 1) * 256 + tid;
    ws[OFF_LAB + wi] = (uint32_t)wi;  // union-find self-init (by rank index)
    ws[OFF_CNT + wi] = 0u;
    uint32_t cB = occ[wi];
    int y = wi >> 4, wx = wi & 15;
    uint32_t lB = wx ? occ[wi - 1] : 0u;
    uint32_t rB = (wx < 15) ? occ[wi + 1] : 0u;
    uint32_t cA = 0, lA = 0, rA = 0, cC = 0, lC = 0, rC = 0;
    if (y > 0) { int wa = wi - WPR; cA = occ[wa]; lA = wx ? occ[wa - 1] : 0u; rA = (wx < 15) ? occ[wa + 1] : 0u; }
    if (y < GRIDW - 1) { int wc = wi + WPR; cC = occ[wc]; lC = wx ? occ[wc - 1] : 0u; rC = (wx < 15) ? occ[wc + 1] : 0u; }
    uint32_t a0, a1, b0, b1, c0, c1;
    hsum(lA, cA, rA, a0, a1); hsum(lB, cB, rB, b0, b1); hsum(lC, cC, rC, c0, c1);
    ws[OFF_CM + wi] = ge5(a0, a1, b0, b1, c0, c1) & cB;
  }
}

// K3: per-cell union of core-core edges (E, S, SE, SW forward neighbors)
__global__ void k_merge(uint32_t* __restrict__ ws) {
  int cell = blockIdx.x * 256 + threadIdx.x;
  const uint32_t* occ = ws + OFF_OCC;
  const uint32_t* cm = ws + OFF_CM;
  const uint32_t* pre = ws + OFF_PRE;
  uint32_t* lab = ws + OFF_LAB;
  int wi = cell >> 5, b = cell & 31, wx = wi & 15;
  uint32_t cw = cm[wi];
  if (!((cw >> b) & 1)) return;
  int y = cell >> 9;
  uint32_t cB = occ[wi];
  int r = pre[wi] + __popc(cB & ((1u << b) - 1u));
  bool eC = (b < 31) ? ((cw >> (b + 1)) & 1) : ((wx < 15) ? (cm[wi + 1] & 1) : false);
  if (eC) unite(lab, r, (b < 31) ? r + 1 : pre[wi + 1]);
  if (y < GRIDW - 1) {
    uint32_t cmS = cm[wi + WPR];
    uint32_t occS = occ[wi + WPR];
    int rS = pre[wi + WPR];
    if ((cmS >> b) & 1) unite(lab, r, rS + __popc(occS & ((1u << b) - 1u)));
    bool seC = (b < 31) ? ((cmS >> (b + 1)) & 1) : ((wx < 15) ? (cm[wi + WPR + 1] & 1) : false);
    if (seC) unite(lab, r, (b < 31) ? rS + __popc(occS & ((2u << b) - 1u)) : pre[wi + WPR + 1]);
    bool swC = (b > 0) ? ((cmS >> (b - 1)) & 1) : ((wx > 0) ? (cm[wi + WPR - 1] >> 31) : false);
    if (swC) unite(lab, r, (b > 0) ? rS + __popc(occS & ((1u << (b - 1)) - 1u)) : rS - 1);
  }
}

// K4: per-cell compress (core) + border attach (non-core) + voxel counts.
// Roots are final after K3; all concurrent writes to a given L entry store
// values on its path to the unique final root, so races are benign.
__global__ void k_cb(uint32_t* __restrict__ ws) {
  int cell = blockIdx.x * 256 + threadIdx.x;
  int wi = cell >> 5, b = cell & 31, wx = wi & 15;
  const uint32_t* occ = ws + OFF_OCC;
  uint32_t cB = occ[wi];
  if (!((cB >> b) & 1)) return;
  const uint32_t* cm = ws + OFF_CM;
  const uint32_t* pre = ws + OFF_PRE;
  uint32_t* lab = ws + OFF_LAB;
  uint32_t* cnt = ws + OFF_CNT;
  int y = cell >> 9;
  uint32_t cw = cm[wi];
  int r = pre[wi] + __popc(cB & ((1u << b) - 1u));
  if ((cw >> b) & 1) {
    uint32_t root = findc(lab, r);
    lab[r] = root;
    if (root == (uint32_t)r) atomicOr(&ws[OFF_ROOTBM + (r >> 5)], 1u << (r & 31));
    atomicAdd(&cnt[root], 1u);
  } else {
    uint32_t m = NONE;
    bool wC = (b > 0) ? ((cw >> (b - 1)) & 1) : ((wx > 0) ? (cm[wi - 1] >> 31) : false);
    if (wC) m = min(m, findc(lab, (b > 0) ? r - 1 : (int)pre[wi] - 1));
    bool eC = (b < 31) ? ((cw >> (b + 1)) & 1) : ((wx < 15) ? (cm[wi + 1] & 1) : false);
    if (eC) m = min(m, findc(lab, (b < 31) ? r + 1 : pre[wi + 1]));
    if (y > 0) {
      uint32_t cmN = cm[wi - WPR], occN = occ[wi - WPR];
      int rN = pre[wi - WPR];
      if ((cmN >> b) & 1) m = min(m, findc(lab, rN + __popc(occN & ((1u << b) - 1u))));
      bool neC = (b < 31) ? ((cmN >> (b + 1)) & 1) : ((wx < 15) ? (cm[wi - WPR + 1] & 1) : false);
      if (neC) m = min(m, findc(lab, (b < 31) ? rN + __popc(occN & ((2u << b) - 1u)) : pre[wi - WPR + 1]));
      bool nwC = (b > 0) ? ((cmN >> (b - 1)) & 1) : ((wx > 0) ? (cm[wi - WPR - 1] >> 31) : false);
      if (nwC) m = min(m, findc(lab, (b > 0) ? rN + __popc(occN & ((1u << (b - 1)) - 1u)) : rN - 1));
    }
    if (y < GRIDW - 1) {
      uint32_t cmS = cm[wi + WPR], occS = occ[wi + WPR];
      int rS = pre[wi + WPR];
      if ((cmS >> b) & 1) m = min(m, findc(lab, rS + __popc(occS & ((1u << b) - 1u))));
      bool seC = (b < 31) ? ((cmS >> (b + 1)) & 1) : ((wx < 15) ? (cm[wi + WPR + 1] & 1) : false);
      if (seC) m = min(m, findc(lab, (b < 31) ? rS + __popc(occS & ((2u << b) - 1u)) : pre[wi + WPR + 1]));
      bool swC = (b > 0) ? ((cmS >> (b - 1)) & 1) : ((wx > 0) ? (cm[wi + WPR - 1] >> 31) : false);
      if (swC) m = min(m, findc(lab, (b > 0) ? rS + __popc(occS & ((1u << (b - 1)) - 1u)) : rS - 1));
    }
    lab[r] = m;  // NONE => noise; non-core ranks are never union-find parents
    if (m != NONE) atomicAdd(&cnt[m], 1u);
  }
}

// K5: dense root numbering, keep filter (>=20 voxels), max kept id -> out[npts]
__global__ void k_finish(uint32_t* __restrict__ ws, float* __restrict__ out,
                         int npts) {
  int tid = threadIdx.x;
  __shared__ uint32_t wsum[4];
  __shared__ int smax;
  if (tid == 0) smax = -1;
  __syncthreads();
  uint32_t rb = ws[OFF_ROOTBM + tid];
  uint32_t v = __popc(rb);
  int lane = tid & 63, wv = tid >> 6;
  uint32_t inc = v;
  for (int d = 1; d < 64; d <<= 1) { uint32_t t = __shfl_up(inc, d); if (lane >= d) inc += t; }
  if (lane == 63) wsum[wv] = inc;
  __syncthreads();
  uint32_t woff = 0;
  for (int k = 0; k < wv; k++) woff += wsum[k];
  uint32_t excl = woff + inc - v;
  ws[OFF_RPRE + tid] = excl;
  uint32_t keep = 0;
  int mx = -1, d = (int)excl;
  while (rb) {
    int b = __ffs(rb) - 1; rb &= rb - 1;
    int r = tid * 32 + b;
    if (ws[OFF_CNT + r] >= 20u) { keep |= 1u << b; mx = d; }
    d++;
  }
  ws[OFF_KEEPBM + tid] = keep;
  if (mx >= 0) atomicMax(&smax, mx);
  __syncthreads();
  if (tid == 0) out[npts] = (float)(smax + 1);
}

// K6: scatter dense labels back to points
__global__ void k_scatter(const float* __restrict__ pts,
                          const uint32_t* __restrict__ ws,
                          float* __restrict__ out, int npts) {
  int i = blockIdx.x * 256 + threadIdx.x;
  if (i >= npts) return;
  float x = pts[i * 5 + 1];
  float y = pts[i * 5 + 2];
  int cx = (int)floorf((x - (-51.2f)) / 0.2f);  // identical math to k_vox
  int cy = (int)floorf((y - (-51.2f)) / 0.2f);
  cx = min(max(cx, 0), GRIDW - 1);
  cy = min(max(cy, 0), GRIDW - 1);
  int cell = cy * GRIDW + cx;
  int wi = cell >> 5;
  int r = ws[OFF_PRE + wi] + __popc(ws[OFF_OCC + wi] & ((1u << (cell & 31)) - 1u));
  uint32_t l = ws[OFF_LAB + r];
  float o = -1.0f;
  if (l != NONE && ((ws[OFF_KEEPBM + (l >> 5)] >> (l & 31)) & 1)) {
    int dnum = ws[OFF_RPRE + (l >> 5)] +
               __popc(ws[OFF_ROOTBM + (l >> 5)] & ((1u << (l & 31)) - 1u));
    o = (float)dnum;
  }
  out[i] = o;
}

extern "C" void kernel_launch(void* const* d_in, const int* in_sizes, int n_in,
                              void* d_out, int out_size, void* d_ws, size_t ws_size,
                              hipStream_t stream) {
  const float* pts = (const float*)d_in[0];
  int npts = in_sizes[0] / 5;  // points are (N,5) float32
  uint32_t* ws = (uint32_t*)d_ws;
  float* out = (float*)d_out;
  int pblocks = (npts + 255) / 256;
  hipMemsetAsync(d_ws, 0, NWORDS * 4, stream);  // occ only
  k_vox<<<pblocks, 256, 0, stream>>>(pts, ws, npts);
  k_scan_cm<<<33, 256, 0, stream>>>(ws);
  k_merge<<<NCELLS / 256, 256, 0, stream>>>(ws);
  k_cb<<<NCELLS / 256, 256, 0, stream>>>(ws);
  k_finish<<<1, 256, 0, stream>>>(ws, out, npts);
  k_scatter<<<pblocks, 256, 0, stream>>>(pts, ws, out, npts);
}